// Round 2
// baseline (143.886 us; speedup 1.0000x reference)
//
#include <hip/hip_runtime.h>
#include <math.h>

#define KEYS 11
#define NSTACK 4
#define NB 16
#define HH 128
#define WW 128
#define HW (HH * WW)

// native vector type so __builtin_nontemporal_load lowers to a 16B nt load
typedef float f4 __attribute__((ext_vector_type(4)));

// One block per (b,k): heat plane is read from HBM exactly ONCE and reused in
// registers for all 4 stacks. Per-(b,s,k) reduction topology (thread->element
// mapping, shuffle tree, wave-merge order) is bit-identical to the previous
// passing kernel; only the k-summation moved to a deterministic finalize pass.
__global__ __launch_bounds__(256) void kp_main(
    const float* __restrict__ cp,    // (16, 4, 22, 128, 128)
    const float* __restrict__ heat,  // (16, 11, 128, 128)
    const float* __restrict__ lab,   // (16, 11, 11)
    float* __restrict__ ws)          // partials: heat[176*4] then label[176*4]
{
    const int grp = blockIdx.x;      // b*KEYS + k
    const int b = grp / KEYS;
    const int k = grp % KEYS;
    const int tid = threadIdx.x;

    const f4* __restrict__ ht4 = (const f4*)(heat + (size_t)grp * HW);
    const f4* __restrict__ hm0 = (const f4*)(cp + ((size_t)((b * NSTACK + 0) * (2 * KEYS) + k)) * HW);
    const f4* __restrict__ hm1 = (const f4*)(cp + ((size_t)((b * NSTACK + 1) * (2 * KEYS) + k)) * HW);
    const f4* __restrict__ hm2 = (const f4*)(cp + ((size_t)((b * NSTACK + 2) * (2 * KEYS) + k)) * HW);
    const f4* __restrict__ hm3 = (const f4*)(cp + ((size_t)((b * NSTACK + 3) * (2 * KEYS) + k)) * HW);

    float sum[NSTACK]  = {0.0f, 0.0f, 0.0f, 0.0f};
    float vmax[NSTACK] = {-INFINITY, -INFINITY, -INFINITY, -INFINITY};
    int   imax[NSTACK] = {0, 0, 0, 0};

    #pragma unroll 4
    for (int i = tid; i < HW / 4; i += 256) {
        f4 c = __builtin_nontemporal_load(ht4 + i);  // read once, reused 4x in regs
        f4 a[NSTACK];
        a[0] = __builtin_nontemporal_load(hm0 + i);
        a[1] = __builtin_nontemporal_load(hm1 + i);
        a[2] = __builtin_nontemporal_load(hm2 + i);
        a[3] = __builtin_nontemporal_load(hm3 + i);
        const int base = i * 4;
        #pragma unroll
        for (int s = 0; s < NSTACK; ++s) {
            float d0 = a[s][0] - c[0], d1 = a[s][1] - c[1];
            float d2 = a[s][2] - c[2], d3 = a[s][3] - c[3];
            sum[s] += d0 * d0 + d1 * d1 + d2 * d2 + d3 * d3;
            // strictly-greater keeps first occurrence (indices increase per thread)
            if (a[s][0] > vmax[s]) { vmax[s] = a[s][0]; imax[s] = base;     }
            if (a[s][1] > vmax[s]) { vmax[s] = a[s][1]; imax[s] = base + 1; }
            if (a[s][2] > vmax[s]) { vmax[s] = a[s][2]; imax[s] = base + 2; }
            if (a[s][3] > vmax[s]) { vmax[s] = a[s][3]; imax[s] = base + 3; }
        }
    }

    // wave-64 reduction per stack (sum + argmax with first-index tie break)
    #pragma unroll
    for (int off = 32; off > 0; off >>= 1) {
        #pragma unroll
        for (int s = 0; s < NSTACK; ++s) {
            float ov = __shfl_down(vmax[s], off);
            int   oi = __shfl_down(imax[s], off);
            float os = __shfl_down(sum[s],  off);
            sum[s] += os;
            if (ov > vmax[s] || (ov == vmax[s] && oi < imax[s])) { vmax[s] = ov; imax[s] = oi; }
        }
    }

    __shared__ float s_sum[4][NSTACK];
    __shared__ float s_v[4][NSTACK];
    __shared__ int   s_i[4][NSTACK];
    const int wave = tid >> 6;
    if ((tid & 63) == 0) {
        #pragma unroll
        for (int s = 0; s < NSTACK; ++s) {
            s_sum[wave][s] = sum[s]; s_v[wave][s] = vmax[s]; s_i[wave][s] = imax[s];
        }
    }
    __syncthreads();

    if (tid < NSTACK) {
        const int s = tid;   // lane s handles stack s
        float fsum = s_sum[0][s];
        float fv   = s_v[0][s];
        int   fi   = s_i[0][s];
        #pragma unroll
        for (int w = 1; w < 4; w++) {
            fsum += s_sum[w][s];
            if (s_v[w][s] > fv || (s_v[w][s] == fv && s_i[w][s] < fi)) {
                fv = s_v[w][s]; fi = s_i[w][s];
            }
        }
        ws[grp * NSTACK + s] = fsum;

        // ---- label loss for (b, s, k) ----
        const float* __restrict__ lb = cp + ((size_t)((b * NSTACK + s) * (2 * KEYS) + KEYS + k)) * HW;
        const float* __restrict__ L  = lab + (size_t)grp * 11;
        float gx = L[9], gy = L[10];
        bool valid = (gx > 0.0f) && (gy > 0.0f) && (gx < (float)HH) && (gy < (float)WW);
        float loss = 0.0f;
        if (valid) {
            float xf = (float)(fi / WW);   // row (x = index // m, m == W == 128)
            float yf = (float)(fi % WW);   // col
            float dx = gx + L[7] - xf - lb[7];
            float dy = gy + L[8] - yf - lb[8];
            loss = dx * dx + dy * dy;
            float cm = 1.0f - fv;
            loss += cm * cm;
            #pragma unroll
            for (int j = 0; j < 7; j++) {
                float d = lb[j] - L[j];
                loss += d * d;
            }
        }
        ws[NB * KEYS * NSTACK + grp * NSTACK + s] = loss;
    }
}

// Deterministic k-sum (ascending) + output write; also replaces the zero-init.
__global__ void kp_final(const float* __restrict__ ws, float* __restrict__ out) {
    const int bs = threadIdx.x;          // 0..63 == b*NSTACK + s
    const int b = bs / NSTACK;
    const int s = bs % NSTACK;
    float h = 0.0f, l = 0.0f;
    #pragma unroll
    for (int k = 0; k < KEYS; ++k) {
        const int g = b * KEYS + k;
        h += ws[g * NSTACK + s];
        l += ws[NB * KEYS * NSTACK + g * NSTACK + s];
    }
    out[bs] = h;
    out[64 + bs] = l;
}

extern "C" void kernel_launch(void* const* d_in, const int* in_sizes, int n_in,
                              void* d_out, int out_size, void* d_ws, size_t ws_size,
                              hipStream_t stream) {
    const float* cp   = (const float*)d_in[0];
    const float* heat = (const float*)d_in[1];
    const float* lab  = (const float*)d_in[2];
    float* out = (float*)d_out;
    float* ws  = (float*)d_ws;   // needs 2 * 176 * 4 floats = 5.5 KB

    kp_main<<<NB * KEYS, 256, 0, stream>>>(cp, heat, lab, ws);
    kp_final<<<1, 64, 0, stream>>>(ws, out);
}

// Round 3
// 134.043 us; speedup vs baseline: 1.0734x; 1.0734x over previous
//
#include <hip/hip_runtime.h>
#include <math.h>

#define KEYS 11
#define NSTACK 4
#define NB 16
#define HH 128
#define WW 128
#define HW (HH * WW)
#define NGRP (NB * KEYS)        // 176
#define NCHUNK 4
#define CF4 (HW / 4 / NCHUNK)   // 1024 f4 elements per chunk

// native vector type so __builtin_nontemporal_load lowers to a 16B nt load
typedef float f4 __attribute__((ext_vector_type(4)));

// ws layout (floats):
//   [0,            2816)  chunk partial sums   [g][c][s]
//   [2816,         5632)  chunk partial vmax   [g][c][s]
//   [5632,         8448)  chunk partial imax   [g][c][s] (int bit-cast)
#define WS_SUM 0
#define WS_V   (NGRP * NCHUNK * NSTACK)
#define WS_I   (2 * NGRP * NCHUNK * NSTACK)

// One block per (b,k,chunk): 704 blocks (full-chip parallelism) AND every
// byte of hm/heat read from HBM exactly once (heat reused in registers
// across the 4 stacks). All loads non-temporal: zero reuse by construction.
__global__ __launch_bounds__(256) void kp_main(
    const float* __restrict__ cp,    // (16, 4, 22, 128, 128)
    const float* __restrict__ heat,  // (16, 11, 128, 128)
    float* __restrict__ ws)
{
    const int bid = blockIdx.x;
    const int c   = bid & (NCHUNK - 1);   // chunk fastest-varying
    const int grp = bid >> 2;             // b*KEYS + k
    const int b = grp / KEYS;
    const int k = grp % KEYS;
    const int tid = threadIdx.x;

    const int coff = c * CF4;             // f4 offset of this chunk
    const f4* __restrict__ ht4 = (const f4*)(heat + (size_t)grp * HW) + coff;
    const f4* __restrict__ hm0 = (const f4*)(cp + ((size_t)((b * NSTACK + 0) * (2 * KEYS) + k)) * HW) + coff;
    const f4* __restrict__ hm1 = (const f4*)(cp + ((size_t)((b * NSTACK + 1) * (2 * KEYS) + k)) * HW) + coff;
    const f4* __restrict__ hm2 = (const f4*)(cp + ((size_t)((b * NSTACK + 2) * (2 * KEYS) + k)) * HW) + coff;
    const f4* __restrict__ hm3 = (const f4*)(cp + ((size_t)((b * NSTACK + 3) * (2 * KEYS) + k)) * HW) + coff;

    float sum[NSTACK]  = {0.0f, 0.0f, 0.0f, 0.0f};
    float vmax[NSTACK] = {-INFINITY, -INFINITY, -INFINITY, -INFINITY};
    int   imax[NSTACK] = {0, 0, 0, 0};

    #pragma unroll
    for (int i = tid; i < CF4; i += 256) {   // 4 iterations, fully unrolled
        f4 cv = __builtin_nontemporal_load(ht4 + i);
        f4 a[NSTACK];
        a[0] = __builtin_nontemporal_load(hm0 + i);
        a[1] = __builtin_nontemporal_load(hm1 + i);
        a[2] = __builtin_nontemporal_load(hm2 + i);
        a[3] = __builtin_nontemporal_load(hm3 + i);
        const int base = (coff + i) * 4;     // global element index in plane
        #pragma unroll
        for (int s = 0; s < NSTACK; ++s) {
            float d0 = a[s][0] - cv[0], d1 = a[s][1] - cv[1];
            float d2 = a[s][2] - cv[2], d3 = a[s][3] - cv[3];
            sum[s] += d0 * d0 + d1 * d1 + d2 * d2 + d3 * d3;
            // strictly-greater keeps first occurrence (indices increase per thread)
            if (a[s][0] > vmax[s]) { vmax[s] = a[s][0]; imax[s] = base;     }
            if (a[s][1] > vmax[s]) { vmax[s] = a[s][1]; imax[s] = base + 1; }
            if (a[s][2] > vmax[s]) { vmax[s] = a[s][2]; imax[s] = base + 2; }
            if (a[s][3] > vmax[s]) { vmax[s] = a[s][3]; imax[s] = base + 3; }
        }
    }

    // wave-64 reduction per stack (sum + argmax with first-index tie break)
    #pragma unroll
    for (int off = 32; off > 0; off >>= 1) {
        #pragma unroll
        for (int s = 0; s < NSTACK; ++s) {
            float ov = __shfl_down(vmax[s], off);
            int   oi = __shfl_down(imax[s], off);
            float os = __shfl_down(sum[s],  off);
            sum[s] += os;
            if (ov > vmax[s] || (ov == vmax[s] && oi < imax[s])) { vmax[s] = ov; imax[s] = oi; }
        }
    }

    __shared__ float s_sum[4][NSTACK];
    __shared__ float s_v[4][NSTACK];
    __shared__ int   s_i[4][NSTACK];
    const int wave = tid >> 6;
    if ((tid & 63) == 0) {
        #pragma unroll
        for (int s = 0; s < NSTACK; ++s) {
            s_sum[wave][s] = sum[s]; s_v[wave][s] = vmax[s]; s_i[wave][s] = imax[s];
        }
    }
    __syncthreads();

    if (tid < NSTACK) {
        const int s = tid;
        float fsum = s_sum[0][s];
        float fv   = s_v[0][s];
        int   fi   = s_i[0][s];
        #pragma unroll
        for (int w = 1; w < 4; w++) {
            fsum += s_sum[w][s];
            if (s_v[w][s] > fv || (s_v[w][s] == fv && s_i[w][s] < fi)) {
                fv = s_v[w][s]; fi = s_i[w][s];
            }
        }
        const int idx = (grp * NCHUNK + c) * NSTACK + s;
        ws[WS_SUM + idx] = fsum;
        ws[WS_V   + idx] = fv;
        ws[WS_I   + idx] = __int_as_float(fi);
    }
}

// Combine chunk partials (ascending chunk order; argmax first-occurrence is
// exact since chunk c's indices are all < chunk c+1's), compute label loss,
// then deterministic ascending-k sums. Replaces zero-init too.
__global__ __launch_bounds__(768) void kp_final(
    const float* __restrict__ cp,
    const float* __restrict__ lab,
    const float* __restrict__ ws,
    float* __restrict__ out)
{
    __shared__ float sh[NGRP * NSTACK];
    __shared__ float sl[NGRP * NSTACK];
    const int t = threadIdx.x;

    if (t < NGRP * NSTACK) {
        const int g = t >> 2;      // b*KEYS + k
        const int s = t & 3;
        const int b = g / KEYS;
        const int k = g % KEYS;

        float fsum = 0.0f;
        float fv   = -INFINITY;
        int   fi   = 0;
        #pragma unroll
        for (int c = 0; c < NCHUNK; ++c) {
            const int idx = (g * NCHUNK + c) * NSTACK + s;
            float ps = ws[WS_SUM + idx];
            float pv = ws[WS_V   + idx];
            int   pi = __float_as_int(ws[WS_I + idx]);
            fsum += ps;
            if (pv > fv || (pv == fv && pi < fi)) { fv = pv; fi = pi; }
        }
        sh[t] = fsum;

        // ---- label loss for (b, s, k) ----
        const float* __restrict__ lb = cp + ((size_t)((b * NSTACK + s) * (2 * KEYS) + KEYS + k)) * HW;
        const float* __restrict__ L  = lab + (size_t)g * 11;
        float gx = L[9], gy = L[10];
        bool valid = (gx > 0.0f) && (gy > 0.0f) && (gx < (float)HH) && (gy < (float)WW);
        float loss = 0.0f;
        if (valid) {
            float xf = (float)(fi / WW);   // row (x = index // m, m == W == 128)
            float yf = (float)(fi % WW);   // col
            float dx = gx + L[7] - xf - lb[7];
            float dy = gy + L[8] - yf - lb[8];
            loss = dx * dx + dy * dy;
            float cm = 1.0f - fv;
            loss += cm * cm;
            #pragma unroll
            for (int j = 0; j < 7; j++) {
                float d = lb[j] - L[j];
                loss += d * d;
            }
        }
        sl[t] = loss;
    }
    __syncthreads();

    if (t < NB * NSTACK) {         // 64 outputs
        const int b = t / NSTACK;
        const int s = t % NSTACK;
        float h = 0.0f, l = 0.0f;
        #pragma unroll
        for (int k = 0; k < KEYS; ++k) {
            const int g = b * KEYS + k;
            h += sh[g * NSTACK + s];
            l += sl[g * NSTACK + s];
        }
        out[t] = h;
        out[64 + t] = l;
    }
}

extern "C" void kernel_launch(void* const* d_in, const int* in_sizes, int n_in,
                              void* d_out, int out_size, void* d_ws, size_t ws_size,
                              hipStream_t stream) {
    const float* cp   = (const float*)d_in[0];
    const float* heat = (const float*)d_in[1];
    const float* lab  = (const float*)d_in[2];
    float* out = (float*)d_out;
    float* ws  = (float*)d_ws;   // needs 3 * 176 * 4 * 4 floats = 33 KB

    kp_main<<<NGRP * NCHUNK, 256, 0, stream>>>(cp, heat, ws);
    kp_final<<<1, 768, 0, stream>>>(cp, lab, ws, out);
}